// Round 4
// baseline (122.542 us; speedup 1.0000x reference)
//
#include <hip/hip_runtime.h>
#include <math.h>

// pred: (1,16,384,384) fp32, labels int32 same shape, area fp32[256]
constexpr int ZN = 16, YN = 384, XN = 384;
constexpr int NZ = 17, NY = 385, NX = 385;   // node grid
constexpr int NP = NY * NX;                  // 148225 nodes per z-slab
constexpr int NROWS = NZ * NY;               // 6545 node rows, one per wave
constexpr int BLOCKS = (NROWS + 3) / 4;      // 1637 blocks x 4 waves

__global__ __launch_bounds__(256) void sd_main(
        const float* __restrict__ pred,
        const int*   __restrict__ labels,
        const float* __restrict__ area,
        int*         __restrict__ counter,   // ws+0, zeroed each launch
        float*       __restrict__ partial,   // ws+16: [num BLOCKS][den BLOCKS][vol BLOCKS]
        float*       __restrict__ out)
{
    // Re-indexed LUT: idx = (own_column_label_nibble << 4) | prev_column_label_nibble
    // original corner k = dz*4+dy*2+dx = 2r+dx, r = 2dz+dy; dx=1 own col, dx=0 prev col.
    __shared__ float s_area[256];
    {
        const int t = threadIdx.x;
        const int own = t >> 4, prv = t & 15;
        int code = 0;
#pragma unroll
        for (int r = 0; r < 4; ++r)
            code |= (((prv >> r) & 1) << (2 * r)) | (((own >> r) & 1) << (2 * r + 1));
        s_area[t] = area[code];
    }
    __syncthreads();

    const int lane = threadIdx.x & 63;
    const int wid  = blockIdx.x * 4 + (threadIdx.x >> 6);

    float num = 0.f, den = 0.f, vol = 0.f;

    if (wid < NROWS) {
        const int z = wid / NY;          // 0..16
        const int y = wid - z * NY;      // 0..384

        bool rv[4]; int base[4];
#pragma unroll
        for (int r = 0; r < 4; ++r) {
            const int zz = z - 1 + (r >> 1);
            const int yy = y - 1 + (r & 1);
            rv[r]   = ((unsigned)zz < (unsigned)ZN) & ((unsigned)yy < (unsigned)YN);
            base[r] = (zz * YN + yy) * XN;
        }

        // node(prev_col, own_col): byte idx = (ownL<<4)|prevL, pw = 1 - (qp+qo)/8
        auto node = [&](const float* sp, float qp, int bp,
                        const float* so, float qo, int bo) {
            const int idxL = ((bo & 15) << 4) | (bp & 15);
            const int idxP = (bo & 0xF0) | (bp >> 4);
            const float la = s_area[idxL];
            const float pa = s_area[idxP];
            const float pw = 1.f - (qp + qo) * 0.125f;
            num = fmaf(2.f * la, pw, num);
            den += la + pa;
            if (idxL == 0 || idxL == 255) {      // interior: labels uniform
                const bool one = (idxL == 255);
                float b = 0.f;
#pragma unroll
                for (int r = 0; r < 4; ++r) {
                    const float up = one ? sp[r] : 1.f - sp[r];
                    const float uo = one ? so[r] : 1.f - so[r];
                    b += __logf(fmaxf(up, 1e-12f)) + __logf(fmaxf(uo, 1e-12f));
                }
                vol -= b;
            }
        };

        float cs[4] = {0.f, 0.f, 0.f, 0.f};   // carry col (x = chunk_end) state
        float cq = 0.f; int cbc = 0;           // (x=-1 pad for chunk 0)

        for (int c = 0; c < 2; ++c) {
            const int xb = c * 192 + lane * 3;   // own columns xb..xb+2 (always in-bounds)
            float s[3][4];
            float q[3]  = {0.f, 0.f, 0.f};
            int   cb[3] = {0, 0, 0};
#pragma unroll
            for (int r = 0; r < 4; ++r) {
                if (rv[r]) {
                    const float* pp = pred + base[r] + xb;
                    const int*   lp = labels + base[r] + xb;
                    float p[3]; int l[3];
#pragma unroll
                    for (int j = 0; j < 3; ++j) { p[j] = pp[j]; l[j] = lp[j]; }
#pragma unroll
                    for (int j = 0; j < 3; ++j) {
                        const float sv = __fdividef(1.f, 1.f + __expf(-p[j]));
                        s[j][r] = sv;
                        const float d = sv - (float)l[j];
                        q[j] = fmaf(d, d, q[j]);
                        cb[j] |= (l[j] << r) | ((int)(p[j] > 0.f) << (r + 4));
                    }
                } else {
#pragma unroll
                    for (int j = 0; j < 3; ++j) s[j][r] = 0.f;  // pad after sigmoid -> 0
                }
            }
            // previous column (x = xb-1) from lane-1 / carry
            float ps[4]; float pq; int pb;
#pragma unroll
            for (int r = 0; r < 4; ++r) ps[r] = __shfl_up(s[2][r], 1);
            pq = __shfl_up(q[2], 1);
            pb = __shfl_up(cb[2], 1);
            if (lane == 0) {
#pragma unroll
                for (int r = 0; r < 4; ++r) ps[r] = cs[r];
                pq = cq; pb = cbc;
            }
            node(ps,   pq,   pb,    s[0], q[0], cb[0]);
            node(s[0], q[0], cb[0], s[1], q[1], cb[1]);
            node(s[1], q[1], cb[1], s[2], q[2], cb[2]);
            // carry lane63 col2 (broadcast to all lanes)
#pragma unroll
            for (int r = 0; r < 4; ++r) cs[r] = __shfl(s[2][r], 63);
            cq  = __shfl(q[2], 63);
            cbc = __shfl(cb[2], 63);
        }
        // final node x = 384: own column is entirely padding (s=0, q=0, bits=0)
        if (lane == 0) {
            const float zs[4] = {0.f, 0.f, 0.f, 0.f};
            node(cs, cq, cbc, zs, 0.f, 0);
        }
    }

    // wave + block reduction
#pragma unroll
    for (int off = 32; off > 0; off >>= 1) {
        num += __shfl_down(num, off);
        den += __shfl_down(den, off);
        vol += __shfl_down(vol, off);
    }
    __shared__ float sn[4], sd_[4], sv[4];
    const int w = threadIdx.x >> 6;
    if (lane == 0) { sn[w] = num; sd_[w] = den; sv[w] = vol; }
    __syncthreads();
    __shared__ bool amLast;
    if (threadIdx.x == 0) {
        partial[blockIdx.x]              = sn[0] + sn[1] + sn[2] + sn[3];
        partial[BLOCKS + blockIdx.x]     = sd_[0] + sd_[1] + sd_[2] + sd_[3];
        partial[2 * BLOCKS + blockIdx.x] = sv[0] + sv[1] + sv[2] + sv[3];
        __threadfence();                               // release partials
        amLast = (atomicAdd(counter, 1) == BLOCKS - 1);
    }
    __syncthreads();

    if (amLast) {
        __threadfence();                               // acquire others' partials
        const volatile float* vp = (const volatile float*)partial;
        double n = 0.0, d = 0.0, v = 0.0;
        for (int b = threadIdx.x; b < BLOCKS; b += 256) {
            n += (double)vp[b];
            d += (double)vp[BLOCKS + b];
            v += (double)vp[2 * BLOCKS + b];
        }
#pragma unroll
        for (int off = 32; off > 0; off >>= 1) {
            n += __shfl_down(n, off);
            d += __shfl_down(d, off);
            v += __shfl_down(v, off);
        }
        __shared__ double dn[4], dd[4], dv[4];
        if (lane == 0) { dn[w] = n; dd[w] = d; dv[w] = v; }
        __syncthreads();
        if (threadIdx.x == 0) {
            const double nn = dn[0] + dn[1] + dn[2] + dn[3];
            const double dd_ = dd[0] + dd[1] + dd[2] + dd[3];
            const double vv = (dv[0] + dv[1] + dv[2] + dv[3]) / (8.0 * (double)NP);
            const double dice = 1.0 - (nn + 1e-3) / (dd_ + 1e-3);
            out[0] = (float)(dice + vv);
        }
    }
}

extern "C" void kernel_launch(void* const* d_in, const int* in_sizes, int n_in,
                              void* d_out, int out_size, void* d_ws, size_t ws_size,
                              hipStream_t stream)
{
    const float* pred   = (const float*)d_in[0];
    const int*   labels = (const int*)d_in[1];
    const float* area   = (const float*)d_in[2];
    float* out     = (float*)d_out;
    int*   counter = (int*)d_ws;                       // ws+0
    float* partial = (float*)((char*)d_ws + 16);       // ws+16, 3*BLOCKS floats

    hipMemsetAsync(counter, 0, 16, stream);
    sd_main<<<BLOCKS, 256, 0, stream>>>(pred, labels, area, counter, partial, out);
}

// Round 5
// 86.705 us; speedup vs baseline: 1.4133x; 1.4133x over previous
//
#include <hip/hip_runtime.h>
#include <math.h>

// pred: (1,16,384,384) fp32, labels int32 same shape, area fp32[256]
constexpr int ZN = 16, YN = 384, XN = 384;
constexpr int NZ = 17, NY = 385, NX = 385;   // node grid
constexpr int NP = NY * NX;                  // 148225 nodes per z-slab
constexpr int NROWS = NZ * NY;               // 6545 node rows, one per wave
constexpr int BLOCKS = (NROWS + 3) / 4;      // 1637 blocks x 4 waves

typedef float F2 __attribute__((ext_vector_type(2)));
typedef int   I2 __attribute__((ext_vector_type(2)));

__global__ __launch_bounds__(256) void sd_main(
        const float* __restrict__ pred,
        const int*   __restrict__ labels,
        const float* __restrict__ area,
        float*       __restrict__ partial)   // [num BLOCKS][den BLOCKS][vol BLOCKS]
{
    // Re-indexed LUT: idx = (own_column_label_nibble << 4) | prev_column_label_nibble
    // original corner k = dz*4+dy*2+dx = 2r+dx, r = 2dz+dy; dx=1 own col, dx=0 prev col.
    __shared__ float s_area[256];
    {
        const int t = threadIdx.x;
        const int own = t >> 4, prv = t & 15;
        int code = 0;
#pragma unroll
        for (int r = 0; r < 4; ++r)
            code |= (((prv >> r) & 1) << (2 * r)) | (((own >> r) & 1) << (2 * r + 1));
        s_area[t] = area[code];
    }
    __syncthreads();

    const int lane = threadIdx.x & 63;
    const int wid  = blockIdx.x * 4 + (threadIdx.x >> 6);

    float num = 0.f, den = 0.f, vol = 0.f;

    if (wid < NROWS) {
        const int z = wid / NY;          // 0..16
        const int y = wid - z * NY;      // 0..384

        // Per-column state: s[j][r] sigmoid, q[j] = sum_r (s-l)^2,
        // cb[j] = label nibble | (pred>0 nibble << 4)
        float s[6][4];
        float q[6]  = {0.f, 0.f, 0.f, 0.f, 0.f, 0.f};
        int   cb[6] = {0, 0, 0, 0, 0, 0};
        const int xb = 6 * lane;         // own voxel columns xb..xb+5 (0..383)

#pragma unroll
        for (int r = 0; r < 4; ++r) {
            const int zz = z - 1 + (r >> 1);
            const int yy = y - 1 + (r & 1);
            const bool rv = ((unsigned)zz < (unsigned)ZN) & ((unsigned)yy < (unsigned)YN);
            if (rv) {
                const int base = (zz * YN + yy) * XN + xb;   // 8B-aligned (base row mult of 384)
                const F2* pp = (const F2*)(pred + base);
                const I2* lp = (const I2*)(labels + base);
                const F2 pa_ = pp[0], pb_ = pp[1], pc_ = pp[2];
                const I2 la_ = lp[0], lb_ = lp[1], lc_ = lp[2];
                const float p[6] = {pa_.x, pa_.y, pb_.x, pb_.y, pc_.x, pc_.y};
                const int   l[6] = {la_.x, la_.y, lb_.x, lb_.y, lc_.x, lc_.y};
#pragma unroll
                for (int j = 0; j < 6; ++j) {
                    const float sv = __fdividef(1.f, 1.f + __expf(-p[j]));   // sigmoid, once/voxel
                    s[j][r] = sv;
                    const float d = sv - (float)l[j];
                    q[j] = fmaf(d, d, q[j]);
                    cb[j] |= (l[j] << r) | ((int)(p[j] > 0.f) << (r + 4));
                }
            } else {
#pragma unroll
                for (int j = 0; j < 6; ++j) s[j][r] = 0.f;   // pad after sigmoid -> exactly 0
            }
        }

        auto node = [&](const float* sp, float qp, int bp,
                        const float* so, float qo, int bo) {
            const int idxL = ((bo & 15) << 4) | (bp & 15);
            const int idxP = (bo & 0xF0) | (bp >> 4);
            const float la = s_area[idxL];
            const float pa = s_area[idxP];
            const float pw = 1.f - (qp + qo) * 0.125f;
            num = fmaf(2.f * la, pw, num);
            den += la + pa;
            if (idxL == 0 || idxL == 255) {      // interior: all 8 labels uniform
                const bool one = (idxL == 255);
                float b = 0.f;
#pragma unroll
                for (int r = 0; r < 4; ++r) {
                    const float up = one ? sp[r] : 1.f - sp[r];
                    const float uo = one ? so[r] : 1.f - so[r];
                    b += __logf(fmaxf(up, 1e-12f)) + __logf(fmaxf(uo, 1e-12f));
                }
                vol -= b;
            }
        };

        // prev column (x = xb-1) = lane-1's column 5; lane 0 -> x=-1 padding (zeros)
        float ps[4]; float pq; int pb;
#pragma unroll
        for (int r = 0; r < 4; ++r) ps[r] = __shfl_up(s[5][r], 1);
        pq = __shfl_up(q[5], 1);
        pb = __shfl_up(cb[5], 1);
        if (lane == 0) { ps[0] = ps[1] = ps[2] = ps[3] = 0.f; pq = 0.f; pb = 0; }

        node(ps,   pq,   pb,    s[0], q[0], cb[0]);
        node(s[0], q[0], cb[0], s[1], q[1], cb[1]);
        node(s[1], q[1], cb[1], s[2], q[2], cb[2]);
        node(s[2], q[2], cb[2], s[3], q[3], cb[3]);
        node(s[3], q[3], cb[3], s[4], q[4], cb[4]);
        node(s[4], q[4], cb[4], s[5], q[5], cb[5]);
        if (lane == 63) {                      // node x=384: own column entirely padding
            const float zs[4] = {0.f, 0.f, 0.f, 0.f};
            node(s[5], q[5], cb[5], zs, 0.f, 0);
        }
    }

    // wave + block reduction
#pragma unroll
    for (int off = 32; off > 0; off >>= 1) {
        num += __shfl_down(num, off);
        den += __shfl_down(den, off);
        vol += __shfl_down(vol, off);
    }
    __shared__ float sn[4], sd_[4], sv[4];
    const int w = threadIdx.x >> 6;
    if (lane == 0) { sn[w] = num; sd_[w] = den; sv[w] = vol; }
    __syncthreads();
    if (threadIdx.x == 0) {
        partial[blockIdx.x]              = sn[0] + sn[1] + sn[2] + sn[3];
        partial[BLOCKS + blockIdx.x]     = sd_[0] + sd_[1] + sd_[2] + sd_[3];
        partial[2 * BLOCKS + blockIdx.x] = sv[0] + sv[1] + sv[2] + sv[3];
    }
}

__global__ __launch_bounds__(256) void sd_final(
        const float* __restrict__ partial, float* __restrict__ out)
{
    double n = 0.0, d = 0.0, v = 0.0;
    for (int b = threadIdx.x; b < BLOCKS; b += 256) {
        n += (double)partial[b];
        d += (double)partial[BLOCKS + b];
        v += (double)partial[2 * BLOCKS + b];
    }
#pragma unroll
    for (int off = 32; off > 0; off >>= 1) {
        n += __shfl_down(n, off);
        d += __shfl_down(d, off);
        v += __shfl_down(v, off);
    }
    __shared__ double sn[4], sd_[4], sv[4];
    const int lane = threadIdx.x & 63, w = threadIdx.x >> 6;
    if (lane == 0) { sn[w] = n; sd_[w] = d; sv[w] = v; }
    __syncthreads();
    if (threadIdx.x == 0) {
        const double num = sn[0] + sn[1] + sn[2] + sn[3];
        const double den = sd_[0] + sd_[1] + sd_[2] + sd_[3];
        const double vol = (sv[0] + sv[1] + sv[2] + sv[3]) / (8.0 * (double)NP);
        const double dice = 1.0 - (num + 1e-3) / (den + 1e-3);
        out[0] = (float)(dice + vol);
    }
}

extern "C" void kernel_launch(void* const* d_in, const int* in_sizes, int n_in,
                              void* d_out, int out_size, void* d_ws, size_t ws_size,
                              hipStream_t stream)
{
    const float* pred   = (const float*)d_in[0];
    const int*   labels = (const int*)d_in[1];
    const float* area   = (const float*)d_in[2];
    float* out     = (float*)d_out;
    float* partial = (float*)d_ws;   // 3*BLOCKS floats, fully overwritten each call

    sd_main<<<BLOCKS, 256, 0, stream>>>(pred, labels, area, partial);
    sd_final<<<1, 256, 0, stream>>>(partial, out);
}